// Round 2
// baseline (390.633 us; speedup 1.0000x reference)
//
#include <hip/hip_runtime.h>
#include <hip/hip_bf16.h>
#include <float.h>

#define IN_F 256
#define HD   128   // H*D
#define NH   4
#define GM   128   // gemm rows per tile

typedef __bf16 bf16x8 __attribute__((ext_vector_type(8)));
typedef __bf16 bf16x2 __attribute__((ext_vector_type(2)));
typedef float  f32x4  __attribute__((ext_vector_type(4)));

__device__ __forceinline__ bf16x8 cvt8(const float4 a, const float4 b) {
    bf16x8 r;
    r[0] = (__bf16)a.x; r[1] = (__bf16)a.y; r[2] = (__bf16)a.z; r[3] = (__bf16)a.w;
    r[4] = (__bf16)b.x; r[5] = (__bf16)b.y; r[6] = (__bf16)b.z; r[7] = (__bf16)b.w;
    return r;
}

// ---------------------------------------------------------------------------
// Pre-swizzle W (128x256 fp32) into MFMA-fragment-major bf16 layout in global:
//   wfrag[((ks*8 + ct)*64 + lane)*8 .. +7] = B[ct*16 + (lane&15)][ks*32 + (lane>>4)*8 + j]
// so a wave's bfrag load for (ks,ct) is one fully-coalesced 16 B/lane read
// (1 KB contiguous). 64 KB total -> L1/L2 resident for every GEMM block.
// ---------------------------------------------------------------------------
__global__ __launch_bounds__(256) void wprep_k(const float* __restrict__ w,
                                               __bf16* __restrict__ wfrag) {
    const int t = threadIdx.x;
    const int col = t >> 1;              // 0..127
    const int k0 = (t & 1) * 128;
    const int ct = col >> 4;
    const float* wp = w + (size_t)col * IN_F + k0;
#pragma unroll
    for (int kk = 0; kk < 128; kk += 8) {
        const float4 v0 = *(const float4*)(wp + kk);
        const float4 v1 = *(const float4*)(wp + kk + 4);
        const int k = k0 + kk;
        const int ks = k >> 5;
        const int lane = (col & 15) + (((k >> 3) & 3) << 4);
        *(bf16x8*)(wfrag + ((size_t)(ks * 8 + ct) * 64 + lane) * 8) = cvt8(v0, v1);
    }
}

// ---------------------------------------------------------------------------
// Zero-LDS, zero-barrier streaming MFMA GEMM + fused deg/rank atomics + fused
// el/er epilogue. One block per 128-row tile (grid = ntiles); wave w owns rows
// wv*32..wv*32+31 (two 16-row m-tiles). A fragments are loaded DIRECTLY from
// feat (lane l covers row frow, k = ks*32 + (l>>4)*8..+7 -> 4 lanes cover one
// row's contiguous 128 B, same coalescing as the old LDS staging); B fragments
// from wfrag (L2-hit, perfectly coalesced). No barriers -> waves drift freely,
// fully-unrolled K-loop exposes ~96 independent loads/wave for latency hiding.
// R1 post-mortem: the old 2-barriers-per-ks LDS pipeline at 2 blocks/CU was
// latency-bound (VALUBusy 4%, HBM 15%); A had zero cross-wave reuse so LDS
// staging was pure cost.
// mfma_f32_16x16x32_bf16; C/D: col=lane&15, row=(lane>>4)*4+reg (verified R2).
// ---------------------------------------------------------------------------
__global__ __launch_bounds__(256) void gemm_fused(const float* __restrict__ feat,
                                                  const __bf16* __restrict__ wfrag,
                                                  const float* __restrict__ attn_l,
                                                  const float* __restrict__ attn_r,
                                                  const int* __restrict__ dst,
                                                  __bf16* __restrict__ ft,
                                                  float* __restrict__ el,
                                                  float* __restrict__ er,
                                                  int* __restrict__ deg,
                                                  int* __restrict__ rank,
                                                  int N, int E) {
    const int t = threadIdx.x;

    // ---- fused deg/rank atomic phase (no barrier: waves flow into GEMM) ----
    for (int i = blockIdx.x * 256 + t; i < E; i += gridDim.x * 256)
        rank[i] = atomicAdd(&deg[dst[i]], 1);

    const int wv = t >> 6;
    const int lane = t & 63;
    const int frow = lane & 15;
    const int fq   = lane >> 4;          // k-quarter 0..3

    // per-lane attn weights for this lane's 8 columns (ct*16+frow)
    float alw[8], arw[8];
#pragma unroll
    for (int ct = 0; ct < 8; ++ct) {
        alw[ct] = attn_l[ct * 16 + frow];
        arw[ct] = attn_r[ct * 16 + frow];
    }

    const int row0 = blockIdx.x * GM;
    const int r0 = row0 + wv * 32 + frow;        // mt=0 fragment row
    const int r1 = r0 + 16;                      // mt=1 fragment row
    const bool ok0 = r0 < N;
    const bool ok1 = r1 < N;
    const float* fA0 = feat + (size_t)r0 * IN_F + fq * 8;
    const float* fA1 = feat + (size_t)r1 * IN_F + fq * 8;
    const __bf16* wfl = wfrag + (size_t)lane * 8;

    f32x4 acc[2][8];
#pragma unroll
    for (int mt = 0; mt < 2; ++mt)
#pragma unroll
        for (int ct = 0; ct < 8; ++ct) acc[mt][ct] = {0.f, 0.f, 0.f, 0.f};

#pragma unroll
    for (int ks = 0; ks < 8; ++ks) {
        bf16x8 af0, af1;
        if (ok0) {
            const float4 a = *(const float4*)(fA0 + ks * 32);
            const float4 b = *(const float4*)(fA0 + ks * 32 + 4);
            af0 = cvt8(a, b);
        } else {
#pragma unroll
            for (int i = 0; i < 8; ++i) af0[i] = (__bf16)0.f;
        }
        if (ok1) {
            const float4 a = *(const float4*)(fA1 + ks * 32);
            const float4 b = *(const float4*)(fA1 + ks * 32 + 4);
            af1 = cvt8(a, b);
        } else {
#pragma unroll
            for (int i = 0; i < 8; ++i) af1[i] = (__bf16)0.f;
        }
#pragma unroll
        for (int ct = 0; ct < 8; ++ct) {
            const bf16x8 bfrag = *(const bf16x8*)(wfl + (size_t)(ks * 8 + ct) * 512);
            acc[0][ct] = __builtin_amdgcn_mfma_f32_16x16x32_bf16(af0, bfrag, acc[0][ct], 0, 0, 0);
            acc[1][ct] = __builtin_amdgcn_mfma_f32_16x16x32_bf16(af1, bfrag, acc[1][ct], 0, 0, 0);
        }
    }

    // ---- epilogue: ft stores (row = (lane>>4)*4 + reg, col = ct*16 + frow) ----
    const int rb = row0 + wv * 32 + (lane >> 4) * 4;
    if (row0 + GM <= N) {
#pragma unroll
        for (int mt = 0; mt < 2; ++mt)
#pragma unroll
            for (int ct = 0; ct < 8; ++ct)
#pragma unroll
                for (int reg = 0; reg < 4; ++reg) {
                    const int m = rb + mt * 16 + reg;
                    ft[(size_t)m * HD + ct * 16 + frow] = (__bf16)acc[mt][ct][reg];
                }
    } else {
#pragma unroll
        for (int mt = 0; mt < 2; ++mt)
#pragma unroll
            for (int ct = 0; ct < 8; ++ct)
#pragma unroll
                for (int reg = 0; reg < 4; ++reg) {
                    const int m = rb + mt * 16 + reg;
                    if (m < N) ft[(size_t)m * HD + ct * 16 + frow] = (__bf16)acc[mt][ct][reg];
                }
    }

    // ---- fused el/er epilogue ----
    // el[r][h] = sum_{ct in {2h,2h+1}} acc*alw, reduced over the 16 frow-lanes
    // of this quarter-group (xor 1,2,4,8 stays within the group).
#pragma unroll
    for (int mt = 0; mt < 2; ++mt) {
#pragma unroll
        for (int reg = 0; reg < 4; ++reg) {
            float pl[4], pr[4];
#pragma unroll
            for (int h = 0; h < 4; ++h) {
                const float v0 = acc[mt][2 * h][reg];
                const float v1 = acc[mt][2 * h + 1][reg];
                pl[h] = v0 * alw[2 * h] + v1 * alw[2 * h + 1];
                pr[h] = v0 * arw[2 * h] + v1 * arw[2 * h + 1];
            }
#pragma unroll
            for (int s = 1; s < 16; s <<= 1) {
#pragma unroll
                for (int h = 0; h < 4; ++h) {
                    pl[h] += __shfl_xor(pl[h], s);
                    pr[h] += __shfl_xor(pr[h], s);
                }
            }
            if (frow == 0) {
                const int r = row0 + wv * 32 + mt * 16 + (lane >> 4) * 4 + reg;
                if (r < N) {
                    *(float4*)(el + (size_t)r * NH) = make_float4(pl[0], pl[1], pl[2], pl[3]);
                    *(float4*)(er + (size_t)r * NH) = make_float4(pr[0], pr[1], pr[2], pr[3]);
                }
            }
        }
    }
}

// ---------------------------------------------------------------------------
// CSR build (scan + scatter; deg/rank produced by gemm_fused)
// ---------------------------------------------------------------------------
__global__ __launch_bounds__(1024) void scan1_k(const int* __restrict__ deg,
                                                int* __restrict__ off,
                                                int* __restrict__ bsum, int N) {
    __shared__ int lds[1024];
    const int t = threadIdx.x;
    const int g = blockIdx.x * 1024 + t;
    const int x = (g < N) ? deg[g] : 0;
    lds[t] = x;
    __syncthreads();
    int v = x;
    for (int s = 1; s < 1024; s <<= 1) {
        const int add = (t >= s) ? lds[t - s] : 0;
        __syncthreads();
        v += add;
        lds[t] = v;
        __syncthreads();
    }
    if (g < N) off[g] = v - x;
    if (t == 1023) bsum[blockIdx.x] = v;
}

__global__ __launch_bounds__(128) void scan2_k(const int* __restrict__ bsum,
                                               int* __restrict__ boff, int nb) {
    __shared__ int lds[128];
    const int t = threadIdx.x;
    const int x = (t < nb) ? bsum[t] : 0;
    lds[t] = x;
    __syncthreads();
    int v = x;
    for (int s = 1; s < 128; s <<= 1) {
        const int add = (t >= s) ? lds[t - s] : 0;
        __syncthreads();
        v += add;
        lds[t] = v;
        __syncthreads();
    }
    boff[t] = v - x;
}

__global__ __launch_bounds__(256) void scatter_k(const int* __restrict__ src,
                                                 const int* __restrict__ dst,
                                                 const int* __restrict__ off,
                                                 const int* __restrict__ boff,
                                                 const int* __restrict__ rank,
                                                 int* __restrict__ ssrc, int E) {
    const int i = blockIdx.x * 256 + threadIdx.x;
    if (i < E) {
        const int d = dst[i];
        const int p = off[d] + boff[d >> 10] + rank[i];
        ssrc[p] = src[i];
    }
}

// ---------------------------------------------------------------------------
// Aggregation: one wave per dst node. (UNCHANGED — measured at its gather-
// pattern roofline: ~245 MB beyond-L2 traffic at ~3.9 TB/s.)
// ---------------------------------------------------------------------------
__global__ __launch_bounds__(64) void aggregate_k(const __bf16* __restrict__ ft,
                                                  const float* __restrict__ el,
                                                  const float* __restrict__ er,
                                                  const int* __restrict__ deg,
                                                  const int* __restrict__ off,
                                                  const int* __restrict__ boff,
                                                  const int* __restrict__ ssrc,
                                                  float* __restrict__ out, int N) {
    const int n = blockIdx.x;
    const int lane = threadIdx.x;
    const int il = lane & 15;       // feature group: f = il*8 .. il*8+7
    const int q  = lane >> 4;       // edge slot within group of 4
    const int h  = il >> 2;         // head of this feature group
    float4* outp = (float4*)(out + (size_t)n * HD);
    const int dn = deg[n];
    if (dn == 0) {
        if (q < 2) outp[il * 2 + q] = make_float4(0.f, 0.f, 0.f, 0.f);
        return;
    }
    const int start = off[n] + boff[n >> 10];
    const float4 er4 = *(const float4*)(er + (size_t)n * NH);

    __shared__ float a_lds[64 * NH];
    __shared__ int   s_lds[64];
    float4 ssum = make_float4(0.f, 0.f, 0.f, 0.f);
    float acc[8];
#pragma unroll
    for (int i = 0; i < 8; ++i) acc[i] = 0.f;

    for (int c0 = 0; c0 < dn; c0 += 64) {
        const int j = c0 + lane;
        float4 a = make_float4(0.f, 0.f, 0.f, 0.f);
        int sv = 0;
        if (j < dn) {
            sv = ssrc[start + j];
            float4 e = *(const float4*)(el + (size_t)sv * NH);
            e.x += er4.x; e.y += er4.y; e.z += er4.z; e.w += er4.w;
            e.x = e.x >= 0.f ? e.x : 0.2f * e.x;
            e.y = e.y >= 0.f ? e.y : 0.2f * e.y;
            e.z = e.z >= 0.f ? e.z : 0.2f * e.z;
            e.w = e.w >= 0.f ? e.w : 0.2f * e.w;
            a.x = __expf(e.x); a.y = __expf(e.y);
            a.z = __expf(e.z); a.w = __expf(e.w);
            ssum.x += a.x; ssum.y += a.y; ssum.z += a.z; ssum.w += a.w;
        }
        s_lds[lane] = sv;
        *(float4*)(a_lds + lane * NH) = a;
        __syncthreads();
        const int cnt = min(64, dn - c0);
        for (int j2 = 0; j2 < cnt; j2 += 8) {   // 8 edges/iter (2 groups of 4)
            const int e0 = j2 + q;
            const int e1 = j2 + 4 + q;
            const int sv0 = s_lds[e0];
            const int sv1 = s_lds[e1];
            const float a0 = a_lds[e0 * NH + h];
            const float a1 = a_lds[e1 * NH + h];
            const bf16x8 f0 = *(const bf16x8*)(ft + (size_t)sv0 * HD + il * 8);
            const bf16x8 f1 = *(const bf16x8*)(ft + (size_t)sv1 * HD + il * 8);
#pragma unroll
            for (int k = 0; k < 8; ++k) acc[k] = fmaf(a0, (float)f0[k], acc[k]);
#pragma unroll
            for (int k = 0; k < 8; ++k) acc[k] = fmaf(a1, (float)f1[k], acc[k]);
        }
        __syncthreads();
    }
#pragma unroll
    for (int s = 1; s < 64; s <<= 1) {
        ssum.x += __shfl_xor(ssum.x, s);
        ssum.y += __shfl_xor(ssum.y, s);
        ssum.z += __shfl_xor(ssum.z, s);
        ssum.w += __shfl_xor(ssum.w, s);
    }
#pragma unroll
    for (int k = 0; k < 8; ++k) {
        acc[k] += __shfl_xor(acc[k], 16);
        acc[k] += __shfl_xor(acc[k], 32);
    }
    const float sumh = (h == 0) ? ssum.x : (h == 1) ? ssum.y : (h == 2) ? ssum.z : ssum.w;
    const float inv = 1.f / sumh;
    if (q < 2) {
        const int b = q * 4;
        outp[il * 2 + q] = make_float4(acc[b] * inv, acc[b + 1] * inv,
                                       acc[b + 2] * inv, acc[b + 3] * inv);
    }
}

// ---------------------------------------------------------------------------
extern "C" void kernel_launch(void* const* d_in, const int* in_sizes, int n_in,
                              void* d_out, int out_size, void* d_ws, size_t ws_size,
                              hipStream_t stream) {
    const float* feat   = (const float*)d_in[0];
    const float* fc_w   = (const float*)d_in[1];
    const float* attn_l = (const float*)d_in[2];
    const float* attn_r = (const float*)d_in[3];
    const int*   src    = (const int*)d_in[4];
    const int*   dst    = (const int*)d_in[5];
    const int N = in_sizes[0] / IN_F;
    const int E = in_sizes[4];
    float* out = (float*)d_out;

    char* wp = (char*)d_ws;
    __bf16* ft = (__bf16*)wp; wp += (size_t)N * HD * 2;  // 25.6 MB
    float* el  = (float*)wp; wp += (size_t)N * NH * 4;   // 1.6 MB
    float* er  = (float*)wp; wp += (size_t)N * NH * 4;   // 1.6 MB
    int* deg   = (int*)wp;   wp += (size_t)N * 4;        // 0.4 MB
    int* off   = (int*)wp;   wp += (size_t)N * 4;        // 0.4 MB
    int* bsum  = (int*)wp;   wp += 1024;
    int* boff  = (int*)wp;   wp += 1024;
    int* rank  = (int*)wp;   wp += (size_t)E * 4;        // 6.4 MB
    int* ssrc  = (int*)wp;   wp += (size_t)E * 4;        // 6.4 MB
    __bf16* wfrag = (__bf16*)wp; wp += (size_t)HD * IN_F * 2;  // 64 KB

    hipMemsetAsync(deg, 0, (size_t)N * 4, stream);

    const int ntiles = (N + GM - 1) / GM;
    wprep_k<<<dim3(1), dim3(256), 0, stream>>>(fc_w, wfrag);
    gemm_fused<<<dim3(ntiles), dim3(256), 0, stream>>>(feat, wfrag, attn_l, attn_r, dst,
                                                       ft, el, er, deg, rank, N, E);
    const int nblk = (N + 1023) >> 10;
    scan1_k<<<dim3(nblk), dim3(1024), 0, stream>>>(deg, off, bsum, N);
    scan2_k<<<dim3(1), dim3(128), 0, stream>>>(bsum, boff, nblk);
    scatter_k<<<dim3((E + 255) / 256), dim3(256), 0, stream>>>(src, dst, off, boff, rank, ssrc, E);
    aggregate_k<<<dim3(N), dim3(64), 0, stream>>>(ft, el, er, deg, off, boff, ssrc, out, N);
}

// Round 3
// 382.004 us; speedup vs baseline: 1.0226x; 1.0226x over previous
//
#include <hip/hip_runtime.h>
#include <hip/hip_bf16.h>
#include <float.h>

#define IN_F 256
#define HD   128   // H*D
#define NH   4
#define GM   128   // gemm rows per tile
#define NA_BLOCKS 242  // atomic-role blocks; 242 + 782 tiles = 1024 = 4 blocks/CU

typedef __bf16 bf16x8 __attribute__((ext_vector_type(8)));
typedef float  f32x4  __attribute__((ext_vector_type(4)));

__device__ __forceinline__ bf16x8 cvt8(const float4 a, const float4 b) {
    bf16x8 r;
    r[0] = (__bf16)a.x; r[1] = (__bf16)a.y; r[2] = (__bf16)a.z; r[3] = (__bf16)a.w;
    r[4] = (__bf16)b.x; r[5] = (__bf16)b.y; r[6] = (__bf16)b.z; r[7] = (__bf16)b.w;
    return r;
}

// ---------------------------------------------------------------------------
// init_k: block 0 pre-swizzles W (128x256 fp32) into MFMA-fragment-major bf16
//   wfrag[((ks*8+ct)*64+lane)*8..+7] = B[ct*16+(lane&15)][ks*32+(lane>>4)*8+j]
// (one coalesced 16B/lane read per (ks,ct) fragment; 64 KB, L2-resident).
// Blocks 1..: zero deg. Replaces the separate wprep_k + hipMemsetAsync
// (2 dispatches -> 1; ~150 us of wall time was inter-dispatch overhead).
// ---------------------------------------------------------------------------
__global__ __launch_bounds__(256) void init_k(const float* __restrict__ w,
                                              __bf16* __restrict__ wfrag,
                                              int* __restrict__ deg, int N) {
    const int t = threadIdx.x;
    if (blockIdx.x == 0) {
        const int col = t >> 1;              // 0..127
        const int k0 = (t & 1) * 128;
        const int ct = col >> 4;
        const float* wp = w + (size_t)col * IN_F + k0;
#pragma unroll
        for (int kk = 0; kk < 128; kk += 8) {
            const float4 v0 = *(const float4*)(wp + kk);
            const float4 v1 = *(const float4*)(wp + kk + 4);
            const int k = k0 + kk;
            const int ks = k >> 5;
            const int lane = (col & 15) + (((k >> 3) & 3) << 4);
            *(bf16x8*)(wfrag + ((size_t)(ks * 8 + ct) * 64 + lane) * 8) = cvt8(v0, v1);
        }
    } else {
        const int base = (blockIdx.x - 1) * 1024 + t * 4;
        if (base + 3 < N) {
            *(int4*)(deg + base) = make_int4(0, 0, 0, 0);
        } else if (base < N) {
            for (int k = base; k < N; ++k) deg[k] = 0;
        }
    }
}

// ---------------------------------------------------------------------------
// Role-split fused kernel (R2 post-mortem: the serial atomic phase WAS the
// whale -- ~90 of 133 us; WRITE_SIZE showed ~49 MB of atomic write-back, and
// two opposite GEMM structures timed identically with all pipes idle).
//   blocks [0, NA_BLOCKS):       deg/rank returning-atomic histogram only
//                                (int4-unrolled, 4 atomics in flight/thread)
//   blocks [NA_BLOCKS, +ntiles): zero-LDS zero-barrier streaming MFMA GEMM
//                                + fused el/er epilogue
// Atomics are fabric-bound, GEMM is HBM/latency-bound -> they overlap on
// disjoint resources; kernel ~ max(phases) instead of sum.
// mfma_f32_16x16x32_bf16; C/D: col=lane&15, row=(lane>>4)*4+reg (verified R2).
// ---------------------------------------------------------------------------
__global__ __launch_bounds__(256) void gemm_fused(const float* __restrict__ feat,
                                                  const __bf16* __restrict__ wfrag,
                                                  const float* __restrict__ attn_l,
                                                  const float* __restrict__ attn_r,
                                                  const int* __restrict__ dst,
                                                  __bf16* __restrict__ ft,
                                                  float* __restrict__ el,
                                                  float* __restrict__ er,
                                                  int* __restrict__ deg,
                                                  int* __restrict__ rank,
                                                  int N, int E) {
    const int t = threadIdx.x;

    if (blockIdx.x < NA_BLOCKS) {
        // ---- atomic role: deg/rank histogram, 4 independent atomics/iter ----
        const int tid = blockIdx.x * 256 + t;
        const int nthr = NA_BLOCKS * 256;
        const int nquad = E >> 2;
        for (int i = tid; i < nquad; i += nthr) {
            const int4 d4 = *(const int4*)(dst + (size_t)i * 4);
            const int r0 = atomicAdd(&deg[d4.x], 1);
            const int r1 = atomicAdd(&deg[d4.y], 1);
            const int r2 = atomicAdd(&deg[d4.z], 1);
            const int r3 = atomicAdd(&deg[d4.w], 1);
            rank[i * 4 + 0] = r0;
            rank[i * 4 + 1] = r1;
            rank[i * 4 + 2] = r2;
            rank[i * 4 + 3] = r3;
        }
        for (int i = (nquad << 2) + tid; i < E; i += nthr)
            rank[i] = atomicAdd(&deg[dst[i]], 1);
        return;
    }

    // ---- GEMM role ----
    const int wv = t >> 6;
    const int lane = t & 63;
    const int frow = lane & 15;
    const int fq   = lane >> 4;          // k-quarter 0..3

    float alw[8], arw[8];
#pragma unroll
    for (int ct = 0; ct < 8; ++ct) {
        alw[ct] = attn_l[ct * 16 + frow];
        arw[ct] = attn_r[ct * 16 + frow];
    }

    const int row0 = (blockIdx.x - NA_BLOCKS) * GM;
    const int r0 = row0 + wv * 32 + frow;        // mt=0 fragment row
    const int r1 = r0 + 16;                      // mt=1 fragment row
    const bool ok0 = r0 < N;
    const bool ok1 = r1 < N;
    const float* fA0 = feat + (size_t)r0 * IN_F + fq * 8;
    const float* fA1 = feat + (size_t)r1 * IN_F + fq * 8;
    const __bf16* wfl = wfrag + (size_t)lane * 8;

    f32x4 acc[2][8];
#pragma unroll
    for (int mt = 0; mt < 2; ++mt)
#pragma unroll
        for (int ct = 0; ct < 8; ++ct) acc[mt][ct] = {0.f, 0.f, 0.f, 0.f};

#pragma unroll
    for (int ks = 0; ks < 8; ++ks) {
        bf16x8 af0, af1;
        if (ok0) {
            const float4 a = *(const float4*)(fA0 + ks * 32);
            const float4 b = *(const float4*)(fA0 + ks * 32 + 4);
            af0 = cvt8(a, b);
        } else {
#pragma unroll
            for (int i = 0; i < 8; ++i) af0[i] = (__bf16)0.f;
        }
        if (ok1) {
            const float4 a = *(const float4*)(fA1 + ks * 32);
            const float4 b = *(const float4*)(fA1 + ks * 32 + 4);
            af1 = cvt8(a, b);
        } else {
#pragma unroll
            for (int i = 0; i < 8; ++i) af1[i] = (__bf16)0.f;
        }
#pragma unroll
        for (int ct = 0; ct < 8; ++ct) {
            const bf16x8 bfrag = *(const bf16x8*)(wfl + (size_t)(ks * 8 + ct) * 512);
            acc[0][ct] = __builtin_amdgcn_mfma_f32_16x16x32_bf16(af0, bfrag, acc[0][ct], 0, 0, 0);
            acc[1][ct] = __builtin_amdgcn_mfma_f32_16x16x32_bf16(af1, bfrag, acc[1][ct], 0, 0, 0);
        }
    }

    // ---- epilogue: ft stores (row = (lane>>4)*4 + reg, col = ct*16 + frow) ----
    const int rb = row0 + wv * 32 + (lane >> 4) * 4;
    if (row0 + GM <= N) {
#pragma unroll
        for (int mt = 0; mt < 2; ++mt)
#pragma unroll
            for (int ct = 0; ct < 8; ++ct)
#pragma unroll
                for (int reg = 0; reg < 4; ++reg) {
                    const int m = rb + mt * 16 + reg;
                    ft[(size_t)m * HD + ct * 16 + frow] = (__bf16)acc[mt][ct][reg];
                }
    } else {
#pragma unroll
        for (int mt = 0; mt < 2; ++mt)
#pragma unroll
            for (int ct = 0; ct < 8; ++ct)
#pragma unroll
                for (int reg = 0; reg < 4; ++reg) {
                    const int m = rb + mt * 16 + reg;
                    if (m < N) ft[(size_t)m * HD + ct * 16 + frow] = (__bf16)acc[mt][ct][reg];
                }
    }

    // ---- fused el/er epilogue ----
#pragma unroll
    for (int mt = 0; mt < 2; ++mt) {
#pragma unroll
        for (int reg = 0; reg < 4; ++reg) {
            float pl[4], pr[4];
#pragma unroll
            for (int h = 0; h < 4; ++h) {
                const float v0 = acc[mt][2 * h][reg];
                const float v1 = acc[mt][2 * h + 1][reg];
                pl[h] = v0 * alw[2 * h] + v1 * alw[2 * h + 1];
                pr[h] = v0 * arw[2 * h] + v1 * arw[2 * h + 1];
            }
#pragma unroll
            for (int s = 1; s < 16; s <<= 1) {
#pragma unroll
                for (int h = 0; h < 4; ++h) {
                    pl[h] += __shfl_xor(pl[h], s);
                    pr[h] += __shfl_xor(pr[h], s);
                }
            }
            if (frow == 0) {
                const int r = row0 + wv * 32 + mt * 16 + (lane >> 4) * 4 + reg;
                if (r < N) {
                    *(float4*)(el + (size_t)r * NH) = make_float4(pl[0], pl[1], pl[2], pl[3]);
                    *(float4*)(er + (size_t)r * NH) = make_float4(pr[0], pr[1], pr[2], pr[3]);
                }
            }
        }
    }
}

// ---------------------------------------------------------------------------
// scan1: per-1024-chunk exclusive scan of deg -> off, chunk totals -> bsum.
// (boff = scan of bsum is now recomputed inline by scatter_k / aggregate_k;
// scan2_k dispatch eliminated.)
// ---------------------------------------------------------------------------
__global__ __launch_bounds__(1024) void scan1_k(const int* __restrict__ deg,
                                                int* __restrict__ off,
                                                int* __restrict__ bsum, int N) {
    __shared__ int lds[1024];
    const int t = threadIdx.x;
    const int g = blockIdx.x * 1024 + t;
    const int x = (g < N) ? deg[g] : 0;
    lds[t] = x;
    __syncthreads();
    int v = x;
    for (int s = 1; s < 1024; s <<= 1) {
        const int add = (t >= s) ? lds[t - s] : 0;
        __syncthreads();
        v += add;
        lds[t] = v;
        __syncthreads();
    }
    if (g < N) off[g] = v - x;
    if (t == 1023) bsum[blockIdx.x] = v;
}

// ---------------------------------------------------------------------------
// scatter: recompute the 98-entry bsum exclusive scan in LDS (replaces the
// scan2_k dispatch), then place each edge's src at CSR position.
// ---------------------------------------------------------------------------
__global__ __launch_bounds__(256) void scatter_k(const int* __restrict__ src,
                                                 const int* __restrict__ dst,
                                                 const int* __restrict__ off,
                                                 const int* __restrict__ bsum,
                                                 const int* __restrict__ rank,
                                                 int* __restrict__ ssrc,
                                                 int E, int nb) {
    __shared__ int lds[128];
    __shared__ int boff_l[128];
    const int t = threadIdx.x;
    int x = 0;
    if (t < 128) {
        x = (t < nb) ? bsum[t] : 0;
        lds[t] = x;
    }
    __syncthreads();
    int v = x;
    for (int s = 1; s < 128; s <<= 1) {
        int add = 0;
        if (t < 128 && t >= s) add = lds[t - s];
        __syncthreads();
        if (t < 128) { v += add; lds[t] = v; }
        __syncthreads();
    }
    if (t < 128) boff_l[t] = v - x;   // exclusive prefix of bsum
    __syncthreads();

    const int i = blockIdx.x * 256 + t;
    if (i < E) {
        const int d = dst[i];
        const int p = off[d] + boff_l[d >> 10] + rank[i];
        ssrc[p] = src[i];
    }
}

// ---------------------------------------------------------------------------
// Aggregation: one wave per dst node. Inner loops UNCHANGED (measured at its
// gather-pattern roofline). Only change: boff[n>>10] recomputed in-wave from
// bsum (<=98 entries, 2 masked loads + shfl reduce) -- kills scan2_k.
// ---------------------------------------------------------------------------
__global__ __launch_bounds__(64) void aggregate_k(const __bf16* __restrict__ ft,
                                                  const float* __restrict__ el,
                                                  const float* __restrict__ er,
                                                  const int* __restrict__ deg,
                                                  const int* __restrict__ off,
                                                  const int* __restrict__ bsum,
                                                  const int* __restrict__ ssrc,
                                                  float* __restrict__ out, int N) {
    const int n = blockIdx.x;
    const int lane = threadIdx.x;
    const int il = lane & 15;       // feature group: f = il*8 .. il*8+7
    const int q  = lane >> 4;       // edge slot within group of 4
    const int h  = il >> 2;         // head of this feature group
    float4* outp = (float4*)(out + (size_t)n * HD);
    const int dn = deg[n];
    if (dn == 0) {
        if (q < 2) outp[il * 2 + q] = make_float4(0.f, 0.f, 0.f, 0.f);
        return;
    }
    // inline boff: exclusive sum of bsum[0 .. (n>>10)-1]
    const int nbi = n >> 10;
    int bo = (lane < nbi) ? bsum[lane] : 0;
    if (lane + 64 < nbi) bo += bsum[lane + 64];
#pragma unroll
    for (int s = 1; s < 64; s <<= 1) bo += __shfl_xor(bo, s);

    const int start = off[n] + bo;
    const float4 er4 = *(const float4*)(er + (size_t)n * NH);

    __shared__ float a_lds[64 * NH];
    __shared__ int   s_lds[64];
    float4 ssum = make_float4(0.f, 0.f, 0.f, 0.f);
    float acc[8];
#pragma unroll
    for (int i = 0; i < 8; ++i) acc[i] = 0.f;

    for (int c0 = 0; c0 < dn; c0 += 64) {
        const int j = c0 + lane;
        float4 a = make_float4(0.f, 0.f, 0.f, 0.f);
        int sv = 0;
        if (j < dn) {
            sv = ssrc[start + j];
            float4 e = *(const float4*)(el + (size_t)sv * NH);
            e.x += er4.x; e.y += er4.y; e.z += er4.z; e.w += er4.w;
            e.x = e.x >= 0.f ? e.x : 0.2f * e.x;
            e.y = e.y >= 0.f ? e.y : 0.2f * e.y;
            e.z = e.z >= 0.f ? e.z : 0.2f * e.z;
            e.w = e.w >= 0.f ? e.w : 0.2f * e.w;
            a.x = __expf(e.x); a.y = __expf(e.y);
            a.z = __expf(e.z); a.w = __expf(e.w);
            ssum.x += a.x; ssum.y += a.y; ssum.z += a.z; ssum.w += a.w;
        }
        s_lds[lane] = sv;
        *(float4*)(a_lds + lane * NH) = a;
        __syncthreads();
        const int cnt = min(64, dn - c0);
        for (int j2 = 0; j2 < cnt; j2 += 8) {   // 8 edges/iter (2 groups of 4)
            const int e0 = j2 + q;
            const int e1 = j2 + 4 + q;
            const int sv0 = s_lds[e0];
            const int sv1 = s_lds[e1];
            const float a0 = a_lds[e0 * NH + h];
            const float a1 = a_lds[e1 * NH + h];
            const bf16x8 f0 = *(const bf16x8*)(ft + (size_t)sv0 * HD + il * 8);
            const bf16x8 f1 = *(const bf16x8*)(ft + (size_t)sv1 * HD + il * 8);
#pragma unroll
            for (int k = 0; k < 8; ++k) acc[k] = fmaf(a0, (float)f0[k], acc[k]);
#pragma unroll
            for (int k = 0; k < 8; ++k) acc[k] = fmaf(a1, (float)f1[k], acc[k]);
        }
        __syncthreads();
    }
#pragma unroll
    for (int s = 1; s < 64; s <<= 1) {
        ssum.x += __shfl_xor(ssum.x, s);
        ssum.y += __shfl_xor(ssum.y, s);
        ssum.z += __shfl_xor(ssum.z, s);
        ssum.w += __shfl_xor(ssum.w, s);
    }
#pragma unroll
    for (int k = 0; k < 8; ++k) {
        acc[k] += __shfl_xor(acc[k], 16);
        acc[k] += __shfl_xor(acc[k], 32);
    }
    const float sumh = (h == 0) ? ssum.x : (h == 1) ? ssum.y : (h == 2) ? ssum.z : ssum.w;
    const float inv = 1.f / sumh;
    if (q < 2) {
        const int b = q * 4;
        outp[il * 2 + q] = make_float4(acc[b] * inv, acc[b + 1] * inv,
                                       acc[b + 2] * inv, acc[b + 3] * inv);
    }
}

// ---------------------------------------------------------------------------
extern "C" void kernel_launch(void* const* d_in, const int* in_sizes, int n_in,
                              void* d_out, int out_size, void* d_ws, size_t ws_size,
                              hipStream_t stream) {
    const float* feat   = (const float*)d_in[0];
    const float* fc_w   = (const float*)d_in[1];
    const float* attn_l = (const float*)d_in[2];
    const float* attn_r = (const float*)d_in[3];
    const int*   src    = (const int*)d_in[4];
    const int*   dst    = (const int*)d_in[5];
    const int N = in_sizes[0] / IN_F;
    const int E = in_sizes[4];
    float* out = (float*)d_out;

    char* wp = (char*)d_ws;
    __bf16* ft = (__bf16*)wp; wp += (size_t)N * HD * 2;  // 25.6 MB
    float* el  = (float*)wp; wp += (size_t)N * NH * 4;   // 1.6 MB
    float* er  = (float*)wp; wp += (size_t)N * NH * 4;   // 1.6 MB
    int* deg   = (int*)wp;   wp += (size_t)N * 4;        // 0.4 MB
    int* off   = (int*)wp;   wp += (size_t)N * 4;        // 0.4 MB
    int* bsum  = (int*)wp;   wp += 1024;
    int* rank  = (int*)wp;   wp += (size_t)E * 4;        // 6.4 MB
    int* ssrc  = (int*)wp;   wp += (size_t)E * 4;        // 6.4 MB
    __bf16* wfrag = (__bf16*)wp; wp += (size_t)HD * IN_F * 2;  // 64 KB

    const int ntiles = (N + GM - 1) / GM;
    const int nblk = (N + 1023) >> 10;

    init_k<<<dim3(1 + nblk), dim3(256), 0, stream>>>(fc_w, wfrag, deg, N);
    gemm_fused<<<dim3(NA_BLOCKS + ntiles), dim3(256), 0, stream>>>(
        feat, wfrag, attn_l, attn_r, dst, ft, el, er, deg, rank, N, E);
    scan1_k<<<dim3(nblk), dim3(1024), 0, stream>>>(deg, off, bsum, N);
    scatter_k<<<dim3((E + 255) / 256), dim3(256), 0, stream>>>(src, dst, off, bsum, rank, ssrc, E, nblk);
    aggregate_k<<<dim3(N), dim3(64), 0, stream>>>(ft, el, er, deg, off, bsum, ssrc, out, N);
}

// Round 4
// 330.764 us; speedup vs baseline: 1.1810x; 1.1549x over previous
//
#include <hip/hip_runtime.h>
#include <hip/hip_bf16.h>
#include <float.h>

#define IN_F 256
#define HD   128   // H*D
#define NH   4
#define GM   128   // gemm rows per tile
#define CHUNK 8192 // edges per histogram/scatter chunk
#define BNODES 256 // nodes per bucket (bucket = dst >> 8)

typedef __bf16 bf16x8 __attribute__((ext_vector_type(8)));
typedef float  f32x4  __attribute__((ext_vector_type(4)));

__device__ __forceinline__ bf16x8 cvt8(const float4 a, const float4 b) {
    bf16x8 r;
    r[0] = (__bf16)a.x; r[1] = (__bf16)a.y; r[2] = (__bf16)a.z; r[3] = (__bf16)a.w;
    r[4] = (__bf16)b.x; r[5] = (__bf16)b.y; r[6] = (__bf16)b.z; r[7] = (__bf16)b.w;
    return r;
}

// ---------------------------------------------------------------------------
// init_k: pre-swizzle W (128x256 fp32) into MFMA-fragment-major bf16:
//   wfrag[((ks*8+ct)*64+lane)*8..+7] = B[ct*16+(lane&15)][ks*32+(lane>>4)*8+j]
// 64 KB, L2-resident for every GEMM block.
// ---------------------------------------------------------------------------
__global__ __launch_bounds__(256) void init_k(const float* __restrict__ w,
                                              __bf16* __restrict__ wfrag) {
    const int t = threadIdx.x;
    const int col = t >> 1;              // 0..127
    const int k0 = (t & 1) * 128;
    const int ct = col >> 4;
    const float* wp = w + (size_t)col * IN_F + k0;
#pragma unroll
    for (int kk = 0; kk < 128; kk += 8) {
        const float4 v0 = *(const float4*)(wp + kk);
        const float4 v1 = *(const float4*)(wp + kk + 4);
        const int k = k0 + kk;
        const int ks = k >> 5;
        const int lane = (col & 15) + (((k >> 3) & 3) << 4);
        *(bf16x8*)(wfrag + ((size_t)(ks * 8 + ct) * 64 + lane) * 8) = cvt8(v0, v1);
    }
}

// ---------------------------------------------------------------------------
// gemm_fused: blocks [0,ntiles) = zero-LDS streaming MFMA GEMM + fused el/er.
// Blocks [ntiles, ntiles+nchunk) = K1 of the atomic-free CSR build: per-chunk
// LDS histogram of dst>>8 into nbucket coarse counters -> cnt[c][b].
// R3 post-mortem: 1.6M returning DEVICE-scope atomics were the ~129us floor
// across three different GEMM structures (R0 evidence: standalone histogram
// and GEMM were each <77us). CSR is now built with LDS atomics only.
// mfma_f32_16x16x32_bf16; C/D: col=lane&15, row=(lane>>4)*4+reg (verified R2).
// ---------------------------------------------------------------------------
__global__ __launch_bounds__(256) void gemm_fused(const float* __restrict__ feat,
                                                  const __bf16* __restrict__ wfrag,
                                                  const float* __restrict__ attn_l,
                                                  const float* __restrict__ attn_r,
                                                  const int* __restrict__ dst,
                                                  __bf16* __restrict__ ft,
                                                  float* __restrict__ el,
                                                  float* __restrict__ er,
                                                  int* __restrict__ cnt,
                                                  int N, int E,
                                                  int ntiles, int nbucket) {
    const int t = threadIdx.x;

    if (blockIdx.x >= ntiles) {
        // ---- K1 role: coarse bucket histogram for one edge chunk ----
        __shared__ int cnt_l[512];       // nbucket <= 512
        const int c = blockIdx.x - ntiles;
        for (int j = t; j < nbucket; j += 256) cnt_l[j] = 0;
        __syncthreads();
        const int e0 = c * CHUNK;
#pragma unroll
        for (int k = 0; k < CHUNK / 256; ++k) {
            const int i = e0 + k * 256 + t;
            if (i < E) atomicAdd(&cnt_l[dst[i] >> 8], 1);
        }
        __syncthreads();
        for (int j = t; j < nbucket; j += 256) cnt[(size_t)c * nbucket + j] = cnt_l[j];
        return;
    }

    // ---- GEMM role ----
    const int wv = t >> 6;
    const int lane = t & 63;
    const int frow = lane & 15;
    const int fq   = lane >> 4;          // k-quarter 0..3

    float alw[8], arw[8];
#pragma unroll
    for (int ct = 0; ct < 8; ++ct) {
        alw[ct] = attn_l[ct * 16 + frow];
        arw[ct] = attn_r[ct * 16 + frow];
    }

    const int row0 = blockIdx.x * GM;
    const int r0 = row0 + wv * 32 + frow;        // mt=0 fragment row
    const int r1 = r0 + 16;                      // mt=1 fragment row
    const bool ok0 = r0 < N;
    const bool ok1 = r1 < N;
    const float* fA0 = feat + (size_t)r0 * IN_F + fq * 8;
    const float* fA1 = feat + (size_t)r1 * IN_F + fq * 8;
    const __bf16* wfl = wfrag + (size_t)lane * 8;

    f32x4 acc[2][8];
#pragma unroll
    for (int mt = 0; mt < 2; ++mt)
#pragma unroll
        for (int ct = 0; ct < 8; ++ct) acc[mt][ct] = {0.f, 0.f, 0.f, 0.f};

#pragma unroll
    for (int ks = 0; ks < 8; ++ks) {
        bf16x8 af0, af1;
        if (ok0) {
            const float4 a = *(const float4*)(fA0 + ks * 32);
            const float4 b = *(const float4*)(fA0 + ks * 32 + 4);
            af0 = cvt8(a, b);
        } else {
#pragma unroll
            for (int i = 0; i < 8; ++i) af0[i] = (__bf16)0.f;
        }
        if (ok1) {
            const float4 a = *(const float4*)(fA1 + ks * 32);
            const float4 b = *(const float4*)(fA1 + ks * 32 + 4);
            af1 = cvt8(a, b);
        } else {
#pragma unroll
            for (int i = 0; i < 8; ++i) af1[i] = (__bf16)0.f;
        }
#pragma unroll
        for (int ct = 0; ct < 8; ++ct) {
            const bf16x8 bfrag = *(const bf16x8*)(wfl + (size_t)(ks * 8 + ct) * 512);
            acc[0][ct] = __builtin_amdgcn_mfma_f32_16x16x32_bf16(af0, bfrag, acc[0][ct], 0, 0, 0);
            acc[1][ct] = __builtin_amdgcn_mfma_f32_16x16x32_bf16(af1, bfrag, acc[1][ct], 0, 0, 0);
        }
    }

    // ---- epilogue: ft stores (row = (lane>>4)*4 + reg, col = ct*16 + frow) ----
    const int rb = row0 + wv * 32 + (lane >> 4) * 4;
    if (row0 + GM <= N) {
#pragma unroll
        for (int mt = 0; mt < 2; ++mt)
#pragma unroll
            for (int ct = 0; ct < 8; ++ct)
#pragma unroll
                for (int reg = 0; reg < 4; ++reg) {
                    const int m = rb + mt * 16 + reg;
                    ft[(size_t)m * HD + ct * 16 + frow] = (__bf16)acc[mt][ct][reg];
                }
    } else {
#pragma unroll
        for (int mt = 0; mt < 2; ++mt)
#pragma unroll
            for (int ct = 0; ct < 8; ++ct)
#pragma unroll
                for (int reg = 0; reg < 4; ++reg) {
                    const int m = rb + mt * 16 + reg;
                    if (m < N) ft[(size_t)m * HD + ct * 16 + frow] = (__bf16)acc[mt][ct][reg];
                }
    }

    // ---- fused el/er epilogue ----
#pragma unroll
    for (int mt = 0; mt < 2; ++mt) {
#pragma unroll
        for (int reg = 0; reg < 4; ++reg) {
            float pl[4], pr[4];
#pragma unroll
            for (int h = 0; h < 4; ++h) {
                const float v0 = acc[mt][2 * h][reg];
                const float v1 = acc[mt][2 * h + 1][reg];
                pl[h] = v0 * alw[2 * h] + v1 * alw[2 * h + 1];
                pr[h] = v0 * arw[2 * h] + v1 * arw[2 * h + 1];
            }
#pragma unroll
            for (int s = 1; s < 16; s <<= 1) {
#pragma unroll
                for (int h = 0; h < 4; ++h) {
                    pl[h] += __shfl_xor(pl[h], s);
                    pr[h] += __shfl_xor(pr[h], s);
                }
            }
            if (frow == 0) {
                const int r = row0 + wv * 32 + mt * 16 + (lane >> 4) * 4 + reg;
                if (r < N) {
                    *(float4*)(el + (size_t)r * NH) = make_float4(pl[0], pl[1], pl[2], pl[3]);
                    *(float4*)(er + (size_t)r * NH) = make_float4(pr[0], pr[1], pr[2], pr[3]);
                }
            }
        }
    }
}

// ---------------------------------------------------------------------------
// K2: per-bucket exclusive scan of cnt over chunks.
//   cnt[c][b] <- sum_{c'<c} cnt[c'][b]   (in place);  total[b] = bucket total.
// One block per bucket, 256 threads (requires nchunk <= 256; here 196).
// ---------------------------------------------------------------------------
__global__ __launch_bounds__(256) void chunkscan_k(int* __restrict__ cnt,
                                                   int* __restrict__ total,
                                                   int nchunk, int nbucket) {
    __shared__ int lds[256];
    const int b = blockIdx.x;
    const int t = threadIdx.x;
    const int x = (t < nchunk) ? cnt[(size_t)t * nbucket + b] : 0;
    lds[t] = x;
    __syncthreads();
    int v = x;
    for (int s = 1; s < 256; s <<= 1) {
        const int add = (t >= s) ? lds[t - s] : 0;
        __syncthreads();
        v += add;
        lds[t] = v;
        __syncthreads();
    }
    if (t < nchunk) cnt[(size_t)t * nbucket + b] = v - x;  // exclusive prefix
    if (t == 255) total[b] = v;                            // bucket total
}

// ---------------------------------------------------------------------------
// K3: coarse scatter into bucket-major order. One block per chunk, 512 thr.
// Each block scans total[] in LDS to get bucket bases, adds its own chunkbase
// (cnt[c][b]) to form per-bucket LDS write cursors, then places each edge as
// an int2 (src,dst). Only LDS atomics; writes are ~nbucket semi-sequential
// streams (vs the old fully-random 4B global scatter).
// Requires nbucket <= 512 (here 391).
// ---------------------------------------------------------------------------
__global__ __launch_bounds__(512) void bscatter_k(const int* __restrict__ src,
                                                  const int* __restrict__ dst,
                                                  const int* __restrict__ cnt,
                                                  const int* __restrict__ total,
                                                  int2* __restrict__ epair,
                                                  int E, int nbucket) {
    __shared__ int lds[512];
    __shared__ int cur[512];
    const int c = blockIdx.x;
    const int t = threadIdx.x;
    const int x = (t < nbucket) ? total[t] : 0;
    lds[t] = x;
    __syncthreads();
    int v = x;
    for (int s = 1; s < 512; s <<= 1) {
        const int add = (t >= s) ? lds[t - s] : 0;
        __syncthreads();
        v += add;
        lds[t] = v;
        __syncthreads();
    }
    // bucketstart (exclusive) + this chunk's base within the bucket
    const int cb = (t < nbucket) ? cnt[(size_t)c * nbucket + t] : 0;
    cur[t] = (v - x) + cb;
    __syncthreads();

    const int e0 = c * CHUNK;
#pragma unroll
    for (int k = 0; k < CHUNK / 512; ++k) {
        const int i = e0 + k * 512 + t;
        if (i < E) {
            const int d = dst[i];
            const int p = atomicAdd(&cur[d >> 8], 1);
            epair[p] = make_int2(src[i], d);
        }
    }
}

// ---------------------------------------------------------------------------
// K4: per-bucket CSR finalize. One block per bucket, 512 threads.
// Pass A: LDS histogram of the bucket's <=256 node slots; LDS scan -> local
// offsets; write deg[] and ABSOLUTE off[]. Pass B: LDS cursors place ssrc
// within the bucket's contiguous window (L2-local). No global atomics.
// ---------------------------------------------------------------------------
__global__ __launch_bounds__(512) void csr_k(const int2* __restrict__ epair,
                                             const int* __restrict__ total,
                                             int* __restrict__ deg,
                                             int* __restrict__ off,
                                             int* __restrict__ ssrc,
                                             int N, int nbucket) {
    __shared__ int lds[512];
    __shared__ int cl[256];
    __shared__ int lcur[256];
    const int b = blockIdx.x;
    const int t = threadIdx.x;

    // scan total[] to get this bucket's segment
    const int x = (t < nbucket) ? total[t] : 0;
    lds[t] = x;
    __syncthreads();
    int v = x;
    for (int s = 1; s < 512; s <<= 1) {
        const int add = (t >= s) ? lds[t - s] : 0;
        __syncthreads();
        v += add;
        lds[t] = v;
        __syncthreads();
    }
    const int tb   = total[b];        // bucket length (L2-hot broadcast)
    const int seg0 = lds[b] - tb;     // exclusive start
    __syncthreads();                  // lds free for reuse

    // Pass A: node histogram
    if (t < 256) cl[t] = 0;
    __syncthreads();
    for (int i = seg0 + t; i < seg0 + tb; i += 512)
        atomicAdd(&cl[epair[i].y & 255], 1);
    __syncthreads();

    // scan cl[256] (512-wide scan, zeros beyond 256)
    const int x2 = (t < 256) ? cl[t] : 0;
    lds[t] = x2;
    __syncthreads();
    int v2 = x2;
    for (int s = 1; s < 512; s <<= 1) {
        const int add = (t >= s) ? lds[t - s] : 0;
        __syncthreads();
        v2 += add;
        lds[t] = v2;
        __syncthreads();
    }
    const int loff = v2 - x2;         // exclusive local offset
    if (t < 256) {
        const int node = b * BNODES + t;
        if (node < N) {
            deg[node] = x2;
            off[node] = seg0 + loff;  // ABSOLUTE offset
        }
        lcur[t] = loff;
    }
    __syncthreads();

    // Pass B: place src values
    for (int i = seg0 + t; i < seg0 + tb; i += 512) {
        const int2 e = epair[i];
        const int p = atomicAdd(&lcur[e.y & 255], 1);
        ssrc[seg0 + p] = e.x;
    }
}

// ---------------------------------------------------------------------------
// Aggregation: one wave per dst node. Inner loops UNCHANGED (measured at its
// gather-pattern roofline ~77us). off[] is now absolute -> boff machinery gone.
// ---------------------------------------------------------------------------
__global__ __launch_bounds__(64) void aggregate_k(const __bf16* __restrict__ ft,
                                                  const float* __restrict__ el,
                                                  const float* __restrict__ er,
                                                  const int* __restrict__ deg,
                                                  const int* __restrict__ off,
                                                  const int* __restrict__ ssrc,
                                                  float* __restrict__ out, int N) {
    const int n = blockIdx.x;
    const int lane = threadIdx.x;
    const int il = lane & 15;       // feature group: f = il*8 .. il*8+7
    const int q  = lane >> 4;       // edge slot within group of 4
    const int h  = il >> 2;         // head of this feature group
    float4* outp = (float4*)(out + (size_t)n * HD);
    const int dn = deg[n];
    if (dn == 0) {
        if (q < 2) outp[il * 2 + q] = make_float4(0.f, 0.f, 0.f, 0.f);
        return;
    }
    const int start = off[n];
    const float4 er4 = *(const float4*)(er + (size_t)n * NH);

    __shared__ float a_lds[64 * NH];
    __shared__ int   s_lds[64];
    float4 ssum = make_float4(0.f, 0.f, 0.f, 0.f);
    float acc[8];
#pragma unroll
    for (int i = 0; i < 8; ++i) acc[i] = 0.f;

    for (int c0 = 0; c0 < dn; c0 += 64) {
        const int j = c0 + lane;
        float4 a = make_float4(0.f, 0.f, 0.f, 0.f);
        int sv = 0;
        if (j < dn) {
            sv = ssrc[start + j];
            float4 e = *(const float4*)(el + (size_t)sv * NH);
            e.x += er4.x; e.y += er4.y; e.z += er4.z; e.w += er4.w;
            e.x = e.x >= 0.f ? e.x : 0.2f * e.x;
            e.y = e.y >= 0.f ? e.y : 0.2f * e.y;
            e.z = e.z >= 0.f ? e.z : 0.2f * e.z;
            e.w = e.w >= 0.f ? e.w : 0.2f * e.w;
            a.x = __expf(e.x); a.y = __expf(e.y);
            a.z = __expf(e.z); a.w = __expf(e.w);
            ssum.x += a.x; ssum.y += a.y; ssum.z += a.z; ssum.w += a.w;
        }
        s_lds[lane] = sv;
        *(float4*)(a_lds + lane * NH) = a;
        __syncthreads();
        const int cnt2 = min(64, dn - c0);
        for (int j2 = 0; j2 < cnt2; j2 += 8) {   // 8 edges/iter (2 groups of 4)
            const int e0 = j2 + q;
            const int e1 = j2 + 4 + q;
            const int sv0 = s_lds[e0];
            const int sv1 = s_lds[e1];
            const float a0 = a_lds[e0 * NH + h];
            const float a1 = a_lds[e1 * NH + h];
            const bf16x8 f0 = *(const bf16x8*)(ft + (size_t)sv0 * HD + il * 8);
            const bf16x8 f1 = *(const bf16x8*)(ft + (size_t)sv1 * HD + il * 8);
#pragma unroll
            for (int k = 0; k < 8; ++k) acc[k] = fmaf(a0, (float)f0[k], acc[k]);
#pragma unroll
            for (int k = 0; k < 8; ++k) acc[k] = fmaf(a1, (float)f1[k], acc[k]);
        }
        __syncthreads();
    }
#pragma unroll
    for (int s = 1; s < 64; s <<= 1) {
        ssum.x += __shfl_xor(ssum.x, s);
        ssum.y += __shfl_xor(ssum.y, s);
        ssum.z += __shfl_xor(ssum.z, s);
        ssum.w += __shfl_xor(ssum.w, s);
    }
#pragma unroll
    for (int k = 0; k < 8; ++k) {
        acc[k] += __shfl_xor(acc[k], 16);
        acc[k] += __shfl_xor(acc[k], 32);
    }
    const float sumh = (h == 0) ? ssum.x : (h == 1) ? ssum.y : (h == 2) ? ssum.z : ssum.w;
    const float inv = 1.f / sumh;
    if (q < 2) {
        const int b = q * 4;
        outp[il * 2 + q] = make_float4(acc[b] * inv, acc[b + 1] * inv,
                                       acc[b + 2] * inv, acc[b + 3] * inv);
    }
}

// ---------------------------------------------------------------------------
extern "C" void kernel_launch(void* const* d_in, const int* in_sizes, int n_in,
                              void* d_out, int out_size, void* d_ws, size_t ws_size,
                              hipStream_t stream) {
    const float* feat   = (const float*)d_in[0];
    const float* fc_w   = (const float*)d_in[1];
    const float* attn_l = (const float*)d_in[2];
    const float* attn_r = (const float*)d_in[3];
    const int*   src    = (const int*)d_in[4];
    const int*   dst    = (const int*)d_in[5];
    const int N = in_sizes[0] / IN_F;
    const int E = in_sizes[4];
    float* out = (float*)d_out;

    const int ntiles  = (N + GM - 1) / GM;
    const int nchunk  = (E + CHUNK - 1) / CHUNK;        // 196 (<=256 required)
    const int nbucket = (N + BNODES - 1) / BNODES;      // 391 (<=512 required)

    char* wp = (char*)d_ws;
    __bf16* ft = (__bf16*)wp; wp += (size_t)N * HD * 2;           // 25.6 MB
    float* el  = (float*)wp; wp += (size_t)N * NH * 4;            // 1.6 MB
    float* er  = (float*)wp; wp += (size_t)N * NH * 4;            // 1.6 MB
    int* deg   = (int*)wp;   wp += (size_t)N * 4;                 // 0.4 MB
    int* off   = (int*)wp;   wp += (size_t)N * 4;                 // 0.4 MB
    int* cnt   = (int*)wp;   wp += (size_t)nchunk * nbucket * 4;  // ~0.3 MB
    int* total = (int*)wp;   wp += (size_t)nbucket * 4 + 64;
    int* ssrc  = (int*)wp;   wp += (size_t)E * 4;                 // 6.4 MB
    int2* epair = (int2*)wp; wp += (size_t)E * 8;                 // 12.8 MB
    __bf16* wfrag = (__bf16*)wp; wp += (size_t)HD * IN_F * 2;     // 64 KB

    init_k<<<dim3(1), dim3(256), 0, stream>>>(fc_w, wfrag);
    gemm_fused<<<dim3(ntiles + nchunk), dim3(256), 0, stream>>>(
        feat, wfrag, attn_l, attn_r, dst, ft, el, er, cnt, N, E, ntiles, nbucket);
    chunkscan_k<<<dim3(nbucket), dim3(256), 0, stream>>>(cnt, total, nchunk, nbucket);
    bscatter_k<<<dim3(nchunk), dim3(512), 0, stream>>>(src, dst, cnt, total, epair, E, nbucket);
    csr_k<<<dim3(nbucket), dim3(512), 0, stream>>>(epair, total, deg, off, ssrc, N, nbucket);
    aggregate_k<<<dim3(N), dim3(64), 0, stream>>>(ft, el, er, deg, off, ssrc, out, N);
}